// Round 12
// baseline (203.654 us; speedup 1.0000x reference)
//
#include <hip/hip_runtime.h>
#include <hip/hip_bf16.h>
#include <cstdint>
#include <cstddef>

#define B_ 512
#define L_ 200
#define D_ 128
#define M_ (B_*L_)
#define T_ 4

typedef short bf16x8 __attribute__((ext_vector_type(8)));
typedef unsigned short u16x8 __attribute__((ext_vector_type(8)));
typedef float f32x4 __attribute__((ext_vector_type(4)));

__device__ __forceinline__ float bf2f(unsigned short u){
  union { unsigned int i; float f; } c; c.i = ((unsigned int)u)<<16; return c.f;
}
__device__ __forceinline__ unsigned short f2bf(float f){
  union { float f; unsigned int i; } c; c.f = f;
  unsigned int r = c.i + 0x7FFFu + ((c.i>>16)&1u);
  return (unsigned short)(r>>16);
}
__device__ __forceinline__ float wsum(float v){
  #pragma unroll
  for (int m=1;m<64;m<<=1) v += __shfl_xor(v, m, 64);
  return v;
}
__device__ __forceinline__ void gload_lds16(const void* g, void* l){
  __builtin_amdgcn_global_load_lds(
      (const __attribute__((address_space(1))) void*)g,
      (__attribute__((address_space(3))) void*)l, 16, 0, 0);
}

// ---------------------------------------------------------------------------
// Weight prep: Wbig[512][384] gate-interleaved (p = dim*4+g) + W2 -> bf16,
// + nb[b] = max(alias[b,0:len])+1 (wave 0 tail work).
// ---------------------------------------------------------------------------
__global__ __launch_bounds__(128)
void k_prepW(const float* __restrict__ w_ih, const float* __restrict__ w_hh,
             const float* __restrict__ W_in, const float* __restrict__ W_out,
             const float* __restrict__ b_in, const float* __restrict__ b_out,
             const float* __restrict__ b_ih, const float* __restrict__ b_hh,
             const float* __restrict__ b_iah, const float* __restrict__ b_ioh,
             const float* __restrict__ W2,
             const int* __restrict__ alias, const int* __restrict__ lens,
             unsigned short* __restrict__ Wbig, float* __restrict__ biasBase,
             float* __restrict__ uIn, float* __restrict__ uOut,
             unsigned short* __restrict__ w2b, int* __restrict__ nb)
{
  const int p = blockIdx.x, t = threadIdx.x;
  if (p < 128) w2b[p*128 + t] = f2bf(W2[p*128 + t]);
  const int dim = p>>2, g = p&3;
  const int row = (g==0) ? dim : (g==1) ? 128+dim : 256+dim;
  const bool has_ih = (g!=3), has_hh = (g!=2);
  __shared__ float wl[128], wrg[128], red[3][128];
  wl[t]  = has_ih ? w_ih[(size_t)row*256 + t]       : 0.f;
  wrg[t] = has_ih ? w_ih[(size_t)row*256 + 128 + t] : 0.f;
  __syncthreads();
  float cin = 0.f, cout = 0.f;
  if (has_ih) {
    for (int m=0;m<128;m++){
      cin  += wl[m]  * W_in [m*128 + t];
      cout += wrg[m] * W_out[m*128 + t];
    }
  }
  Wbig[(size_t)p*384 +       t] = f2bf(cin);
  Wbig[(size_t)p*384 + 128 + t] = f2bf(cout);
  Wbig[(size_t)p*384 + 256 + t] = f2bf(has_hh ? w_hh[(size_t)row*128 + t] : 0.f);
  red[0][t] = wl[t]*b_iah[t] + wrg[t]*b_ioh[t];
  red[1][t] = wl[t]*b_in[t];
  red[2][t] = wrg[t]*b_out[t];
  __syncthreads();
  if (t == 0) {
    float v=0.f, ui=0.f, uo=0.f;
    for (int k=0;k<128;k++){ v += red[0][k]; ui += red[1][k]; uo += red[2][k]; }
    float bb;
    if (g==0)      bb = b_ih[dim]     + b_hh[dim]     + v;
    else if (g==1) bb = b_ih[128+dim] + b_hh[128+dim] + v;
    else if (g==2) bb = b_ih[256+dim] + v;
    else           bb = b_hh[256+dim];
    biasBase[p] = bb;
    uIn[p]  = has_ih ? ui : 0.f;
    uOut[p] = has_ih ? uo : 0.f;
  }
  if (t < 64) {
    const int len = lens[p];
    int m = 0;
    for (int l=t; l<len; l+=64) m = max(m, alias[p*L_ + l]);
    #pragma unroll
    for (int o=1;o<64;o<<=1) m = max(m, __shfl_xor(m, o, 64));
    if (t==0) nb[p] = m + 1;
  }
}

// ---------------------------------------------------------------------------
// Exclusive prefix sums of nb and len -> nbase[513], vbase[513]
// ---------------------------------------------------------------------------
__global__ __launch_bounds__(512)
void k_scan(const int* __restrict__ nb, const int* __restrict__ lens,
            int* __restrict__ nbase, int* __restrict__ vbase)
{
  __shared__ int A[2][512], Bv[2][512];
  const int t = threadIdx.x;
  const int a0 = nb[t], b0 = lens[t];
  A[0][t] = a0; Bv[0][t] = b0;
  __syncthreads();
  int cur = 0;
  for (int off=1; off<512; off<<=1){
    const int nxt = cur^1;
    A[nxt][t]  = A[cur][t]  + (t>=off ? A[cur][t-off]  : 0);
    Bv[nxt][t] = Bv[cur][t] + (t>=off ? Bv[cur][t-off] : 0);
    __syncthreads();
    cur = nxt;
  }
  nbase[t] = A[cur][t] - a0;
  vbase[t] = Bv[cur][t] - b0;
  if (t==511){ nbase[512] = A[cur][511]; vbase[512] = Bv[cur][511]; }
}

// ---------------------------------------------------------------------------
// Fused embedding gather + graph aggregation -> COMPACT X3 rows + gidx map.
// ---------------------------------------------------------------------------
__global__ __launch_bounds__(1024)
void k_aggemb(const int* __restrict__ alias, const int* __restrict__ items,
              const int* __restrict__ lens, const float* __restrict__ emb,
              const int* __restrict__ nb, const int* __restrict__ nbase,
              const int* __restrict__ vbase,
              unsigned short* __restrict__ X3, unsigned char* __restrict__ cf,
              int* __restrict__ gidx)
{
  const int b = blockIdx.x, tid = threadIdx.x;
  __shared__ unsigned short hl[L_*128];        // 50KB
  __shared__ int al[L_], it[L_];
  __shared__ unsigned bmIn[L_*8], bmOut[L_*8]; // 12.8KB
  if (tid < L_) { al[tid] = alias[b*L_ + tid]; it[tid] = items[b*L_ + tid]; }
  for (int i=tid; i<L_*8; i+=1024){ bmIn[i]=0u; bmOut[i]=0u; }
  __syncthreads();
  const int len = lens[b], nB = nb[b], base = nbase[b];
  if (tid < len) gidx[vbase[b] + tid] = base + al[tid];
  if (tid < len-1) {
    const int r = al[tid], c = al[tid+1];
    atomicOr(&bmIn[c*8 + (r>>5)],  1u<<(r&31));
    atomicOr(&bmOut[r*8 + (c>>5)], 1u<<(c&31));
  }
  const int rr = tid>>5, cc = (tid&31)<<2;
  for (int s=0; s<nB; s+=32) {
    const int j = s + rr;
    if (j < nB) {
      const float4 v = *(const float4*)(emb + (size_t)it[j]*128 + cc);
      ushort4 o; o.x=f2bf(v.x); o.y=f2bf(v.y); o.z=f2bf(v.z); o.w=f2bf(v.w);
      *(ushort4*)(hl + j*128 + cc) = o;
      *(ushort4*)(X3 + (size_t)(base + j)*384 + 256 + cc) = o;
    }
  }
  __syncthreads();
  const int g = tid >> 7, d = tid & 127;
  for (int s=0; s<nB; s+=8) {
    const int i = s + g;
    if (i < nB) {
      float si=0.f, so=0.f; int ci=0, co=0;
      #pragma unroll
      for (int wd=0; wd<8; ++wd) {
        unsigned word = bmIn[i*8+wd];
        while (word) { int j = __ffs(word)-1; word &= word-1u;
          si += bf2f(hl[(wd*32+j)*128 + d]); ci++; }
        word = bmOut[i*8+wd];
        while (word) { int j = __ffs(word)-1; word &= word-1u;
          so += bf2f(hl[(wd*32+j)*128 + d]); co++; }
      }
      unsigned short* xr = X3 + (size_t)(base + i)*384;
      xr[d]       = f2bf(si / (float)(ci>0?ci:1));
      xr[128 + d] = f2bf(so / (float)(co>0?co:1));
      if (d == 0) cf[base + i] = (unsigned char)((ci>0?1:0) | (co>0?2:0));
    }
  }
}

// ---------------------------------------------------------------------------
// Fused gates GEMM + GRU + Q0 GEMM.
// Gates run in TWO N-halves (pcols 0:256, 256:512) with the R10-proven
// 48KB 2-phase structure -> 3 blocks/CU. Each block thus owns all 128 dims
// of its 128 rows. After the last K-loop, sB (32KB) is dead -> reused as the
// hidden tile hl[128][128] (slot-swizzled); half-0 GRU results carried in 8
// packed VGPRs, half-1 written directly. W2 B-fragments read from global
// (32KB, L2-hot) into registers. Q0 = hl @ W2^T in-block.
// ---------------------------------------------------------------------------
__global__ __launch_bounds__(512)
void k_gates_q0(const unsigned short* __restrict__ X3,
                const unsigned short* __restrict__ Wbig,
                const unsigned short* __restrict__ w2b,
                const float* __restrict__ biasBase,
                const float* __restrict__ uIn,
                const float* __restrict__ uOut,
                const unsigned char* __restrict__ cf,
                unsigned short* __restrict__ hidden,
                unsigned short* __restrict__ q0n,
                const int* __restrict__ mlimit)
{
  const int m0 = blockIdx.x * 128;
  if (m0 >= *mlimit) return;
  __shared__ __align__(16) short sA[2][128*32];   // 16KB
  __shared__ __align__(16) short sB[2][256*32];   // 32KB  (total 48KB)
  const int tid = threadIdx.x;
  const int lane = tid & 63;
  const int w = tid >> 6;
  const int wr  = (w>>2)*64;
  const int wcp = (w&3)*64;
  const int fr = lane & 15;
  const int fq = lane >> 4;
  const int fk = ((fq ^ ((fr>>1)&3))&3)<<3;

  const int ra = tid>>2, sa_ = tid&3, ka = ((sa_ ^ ((ra>>1)&3))&3)<<3;
  const int c1 = tid + 512, rb1 = c1>>2, sb1 = c1&3, kb1 = ((sb1 ^ ((rb1>>1)&3))&3)<<3;

  short* hl = &sB[0][0];              // [128][128] bf16 overlay (32KB)
  unsigned hv0p[8];                   // half-0 GRU results, packed 2x bf16
  const bool q0b_ = (lane & 1), q1b_ = (lane & 2);

  for (int half=0; half<2; ++half){
    const int p0 = half << 8;
    f32x4 acc[4][4];
    #pragma unroll
    for (int i=0;i<4;i++)
      #pragma unroll
      for (int j=0;j<4;j++) acc[i][j] = (f32x4){0.f,0.f,0.f,0.f};

    auto stage = [&](int t){
      const int buf = t & 1, ks = t << 5;
      gload_lds16(X3   + (size_t)(m0 + ra )*384 + ks + ka , sA[buf] + (size_t)tid*8);
      gload_lds16(Wbig + (size_t)(p0 + ra )*384 + ks + ka , sB[buf] + (size_t)tid*8);
      gload_lds16(Wbig + (size_t)(p0 + rb1)*384 + ks + kb1, sB[buf] + 4096 + (size_t)tid*8);
    };
    stage(0);
    __syncthreads();
    for (int t=0; t<12; ++t){
      if (t < 11) stage(t+1);
      const short* a_ = sA[t&1];
      const short* b_ = sB[t&1];
      bf16x8 af[4], bfr[4];
      #pragma unroll
      for (int i=0;i<4;i++){
        af[i]  = *(const bf16x8*)(a_ + (wr  + i*16 + fr)*32 + fk);
        bfr[i] = *(const bf16x8*)(b_ + (wcp + i*16 + fr)*32 + fk);
      }
      #pragma unroll
      for (int i=0;i<4;i++)
        #pragma unroll
        for (int j=0;j<4;j++)
          acc[i][j] = __builtin_amdgcn_mfma_f32_16x16x32_bf16(af[i], bfr[j], acc[i][j], 0,0,0);
      __syncthreads();
    }

    // GRU epilogue for dims half*64 .. half*64+63.
    #pragma unroll
    for (int j=0;j<4;j++){
      const int dim = half*64 + (w&3)*16 + j*4 + ((lane>>2)&3);
      const float4 bb = *(const float4*)(biasBase + dim*4);
      const float4 bi = *(const float4*)(uIn  + dim*4);
      const float4 bo = *(const float4*)(uOut + dim*4);
      #pragma unroll
      for (int i=0;i<4;i++){
        const float a0=acc[i][j][0], a1=acc[i][j][1], a2=acc[i][j][2], a3=acc[i][j][3];
        const float t0=__shfl_xor(a0,1), t1=__shfl_xor(a1,1), t2=__shfl_xor(a2,1), t3=__shfl_xor(a3,1);
        const float s0 = q0b_? t1:a0, s1 = q0b_? a1:t0, s2 = q0b_? t3:a2, s3 = q0b_? a3:t2;
        const float u0=__shfl_xor(s0,2), u1=__shfl_xor(s1,2), u2=__shfl_xor(s2,2), u3=__shfl_xor(s3,2);
        float G0 = q1b_? u2:s0, G1 = q1b_? u3:s1, G2 = q1b_? s2:u0, G3 = q1b_? s3:u1;
        const int row = m0 + wr + i*16 + fq*4 + (lane&3);
        const unsigned c = cf[row];
        const float fi = (c&1) ? 1.f : 0.f, fo = (c&2) ? 1.f : 0.f;
        G0 += bb.x + fi*bi.x + fo*bo.x;
        G1 += bb.y + fi*bi.y + fo*bo.y;
        G2 += bb.z + fi*bi.z + fo*bo.z;
        G3 += bb.w;
        const float h = bf2f(X3[(size_t)row*384 + 256 + dim]);
        const float r = 1.f/(1.f+__expf(-G0));
        const float z = 1.f/(1.f+__expf(-G1));
        const float x = G2 + r*G3;
        const float n = 1.f - 2.f/(__expf(2.f*x)+1.f);   // tanh
        const unsigned short hvv = f2bf((1.f-z)*h + z*n);
        hidden[(size_t)row*128 + dim] = hvv;
        if (half == 0) {
          const int pi = j*2 + (i>>1);
          if ((i&1)==0) hv0p[pi] = hvv;
          else          hv0p[pi] |= ((unsigned)hvv << 16);
        } else {
          const int rl = row - m0;
          hl[rl*128 + (((dim>>3) ^ (rl&7))<<3) + (dim&7)] = (short)hvv;
        }
      }
    }
  }

  // Spill half-0 results into hl (sB dead after last K-loop sync).
  #pragma unroll
  for (int j=0;j<4;j++){
    const int dim = (w&3)*16 + j*4 + ((lane>>2)&3);
    #pragma unroll
    for (int i=0;i<4;i++){
      const int rl = wr + i*16 + fq*4 + (lane&3);
      const unsigned short hvv =
        (unsigned short)((i&1) ? (hv0p[j*2+(i>>1)] >> 16) : (hv0p[j*2+(i>>1)] & 0xFFFFu));
      hl[rl*128 + (((dim>>3) ^ (rl&7))<<3) + (dim&7)] = (short)hvv;
    }
  }

  // Preload W2 fragments from global (L2-hot, 32KB).
  const int wc2 = (w&3)*32;
  bf16x8 bw[2][4];
  #pragma unroll
  for (int j=0;j<2;j++)
    #pragma unroll
    for (int kk=0;kk<4;kk++)
      bw[j][kk] = *(const bf16x8*)(w2b + (size_t)(wc2 + j*16 + fr)*128 + kk*32 + fq*8);
  __syncthreads();

  // Q0 = hl @ W2^T, output 128x128. Wave tile: 64 rows x 32 cols.
  f32x4 acc2[4][2];
  #pragma unroll
  for (int i=0;i<4;i++){ acc2[i][0]=(f32x4){0,0,0,0}; acc2[i][1]=(f32x4){0,0,0,0}; }
  #pragma unroll
  for (int kk=0;kk<4;kk++){
    bf16x8 af2[4];
    #pragma unroll
    for (int i=0;i<4;i++){
      const int r = wr + i*16 + fr;
      af2[i] = *(const bf16x8*)(hl + r*128 + (((kk*4 + fq) ^ (r&7))<<3));
    }
    #pragma unroll
    for (int i=0;i<4;i++)
      #pragma unroll
      for (int j=0;j<2;j++)
        acc2[i][j] = __builtin_amdgcn_mfma_f32_16x16x32_bf16(af2[i], bw[j][kk], acc2[i][j], 0,0,0);
  }
  #pragma unroll
  for (int i=0;i<4;i++){
    #pragma unroll
    for (int j=0;j<2;j++){
      const int col = wc2 + j*16 + fr;
      #pragma unroll
      for (int v=0;v<4;v++){
        const int row = m0 + wr + i*16 + fq*4 + v;
        q0n[(size_t)row*128 + col] = f2bf(acc2[i][j][v]);
      }
    }
  }
}

// ---------------------------------------------------------------------------
// LN + LIF + alpha + masked sum over compact valid rows, THEN the final
// sh=[a,ht] LIF + LN + @Wt.T + mean_T — all in one per-batch block.
// Q0 read per NODE row via gidx (q0n).
// ---------------------------------------------------------------------------
__global__ __launch_bounds__(1024)
void k_attn(const unsigned short* __restrict__ q0n,
            const unsigned short* __restrict__ hidden, const int* __restrict__ gidx,
            const int* __restrict__ lens, const int* __restrict__ vbase,
            const float* __restrict__ W1,
            const float* __restrict__ g_q, const float* __restrict__ beta_q,
            const float* __restrict__ W3,
            const float* __restrict__ g_sh, const float* __restrict__ beta_sh,
            const float* __restrict__ Wt, float* __restrict__ out)
{
  const int b = blockIdx.x, tid = threadIdx.x;
  const int w = tid>>6, lane = tid&63;
  __shared__ float a_acc[16][T_][128];
  __shared__ float htv[128], htw[128];
  __shared__ float ys[256];
  __shared__ float part[T_][4];
  const int len = lens[b], vb = vbase[b];
  for (int i=tid; i<16*T_*128; i+=1024) ((float*)a_acc)[i] = 0.f;
  if (tid < 128) htv[tid] = bf2f(hidden[(size_t)gidx[vb + len - 1]*128 + tid]);
  __syncthreads();
  {  // htw[d] = sum_k W1[d][k] * htv[k]; 8 threads per dim.
    const int d = tid >> 3, seg = (tid & 7) << 4;
    const float* wr1 = W1 + (size_t)d*128 + seg;
    const float* hv = htv + seg;
    float p = 0.f;
    #pragma unroll
    for (int k=0;k<16;k++) p += wr1[k]*hv[k];
    p += __shfl_xor(p, 1, 64); p += __shfl_xor(p, 2, 64); p += __shfl_xor(p, 4, 64);
    if ((tid & 7) == 0) htw[d] = p;
  }
  __syncthreads();
  const float h0 = htw[lane], h1 = htw[lane+64];
  const float gq0 = g_q[lane], gq1 = g_q[lane+64];
  const float bq0 = beta_q[lane], bq1 = beta_q[lane+64];
  const float w30 = W3[lane], w31 = W3[lane+64];
  for (int l = w; l < len; l += 16) {
    const size_t row = (size_t)(vb + l);
    const size_t hrow = (size_t)gidx[row];
    const float q0 = bf2f(q0n[hrow*128 + lane]) + h0;
    const float q1 = bf2f(q0n[hrow*128 + lane + 64]) + h1;
    const float m = wsum(q0+q1) * (1.f/128.f);
    const float d0 = q0-m, d1 = q1-m;
    const float var = wsum(d0*d0 + d1*d1) * (1.f/128.f);
    const float inv = rsqrtf(var + 1e-5f);
    const float x0 = d0*inv*gq0 + bq0;
    const float x1 = d1*inv*gq1 + bq1;
    const float sh0 = bf2f(hidden[hrow*128+lane]), sh1 = bf2f(hidden[hrow*128+lane+64]);
    float v0=0.f, v1=0.f;
    #pragma unroll
    for (int t=0;t<T_;t++){
      v0 = 0.5f*(v0+x0); v1 = 0.5f*(v1+x1);
      const float s0 = (v0>=1.f)?1.f:0.f, s1 = (v1>=1.f)?1.f:0.f;
      v0 -= s0*v0; v1 -= s1*v1;
      const float alpha = wsum(s0*w30 + s1*w31);
      a_acc[w][t][lane] += alpha*sh0; a_acc[w][t][lane+64] += alpha*sh1;
    }
  }
  __syncthreads();

  // ---- final stage: sh=[a,ht] LIF, LN(binary), @Wt, mean_T ----
  float sp[T_] = {0.f,0.f,0.f,0.f};
  if (tid < 256) {
    const float xh = (tid >= 128) ? htv[tid-128] : 0.f;
    float v = 0.f;
    #pragma unroll
    for (int t=0;t<T_;t++){
      float x;
      if (tid < 128) {
        x = 0.f;
        #pragma unroll
        for (int p=0;p<16;p++) x += a_acc[p][t][tid];
      } else x = xh;
      v = 0.5f*(v + x);
      const float s = (v>=1.f)?1.f:0.f;
      v -= s*v;
      sp[t] = s;
    }
    #pragma unroll
    for (int t=0;t<T_;t++){
      const float r = wsum(sp[t]);
      if (lane==0) part[t][w] = r;
    }
  }
  __syncthreads();
  if (tid < 256) {
    float acc4 = 0.f;
    #pragma unroll
    for (int t=0;t<T_;t++){
      const float k = part[t][0]+part[t][1]+part[t][2]+part[t][3];
      const float mean = k * (1.f/256.f);
      const float varr = mean - mean*mean;   // spikes binary: E[x^2]=E[x]
      const float inv = rsqrtf(varr + 1e-5f);
      acc4 += (sp[t]-mean)*inv;
    }
    ys[tid] = acc4*g_sh[tid] + 4.f*beta_sh[tid];
  }
  __syncthreads();
  if (tid < 128) {
    float acc = 0.f;
    const float4* wr4 = (const float4*)(Wt + (size_t)tid*256);
    const float4* ys4 = (const float4*)ys;
    #pragma unroll 8
    for (int k=0;k<64;k++){
      const float4 wv = wr4[k], yv = ys4[k];
      acc += wv.x*yv.x + wv.y*yv.y + wv.z*yv.z + wv.w*yv.w;
    }
    out[(size_t)b*128 + tid] = acc*0.25f;
  }
}

// ---------------------------------------------------------------------------
extern "C" void kernel_launch(void* const* d_in, const int* in_sizes, int n_in,
                              void* d_out, int out_size, void* d_ws, size_t ws_size,
                              hipStream_t stream)
{
  const int*   alias  = (const int*)d_in[1];
  const int*   items  = (const int*)d_in[2];
  const int*   lens   = (const int*)d_in[4];
  const float* emb    = (const float*)d_in[5];
  const float* W_in   = (const float*)d_in[6];
  const float* b_in   = (const float*)d_in[7];
  const float* W_out  = (const float*)d_in[8];
  const float* b_out  = (const float*)d_in[9];
  const float* w_ih   = (const float*)d_in[10];
  const float* w_hh   = (const float*)d_in[11];
  const float* b_ih   = (const float*)d_in[12];
  const float* b_hh   = (const float*)d_in[13];
  const float* b_iah  = (const float*)d_in[14];
  const float* b_ioh  = (const float*)d_in[15];
  const float* W1     = (const float*)d_in[16];
  const float* W2     = (const float*)d_in[17];
  const float* W3     = (const float*)d_in[18];
  const float* Wt     = (const float*)d_in[19];
  const float* g_q    = (const float*)d_in[20];
  const float* beta_q = (const float*)d_in[21];
  const float* g_sh   = (const float*)d_in[22];
  const float* beta_sh= (const float*)d_in[23];

  char* ws = (char*)d_ws;
  size_t off = 0;
  auto alloc = [&](size_t bytes)->void* {
    void* p = ws + off; off += (bytes + 255) & ~(size_t)255; return p;
  };
  unsigned short* X3    = (unsigned short*)alloc((size_t)M_*384*2);   // compact
  unsigned short* hidden= (unsigned short*)alloc((size_t)M_*128*2);   // compact
  unsigned short* q0n   = (unsigned short*)alloc((size_t)M_*128*2);   // compact (node rows)
  int*            gidx  = (int*)alloc((size_t)M_*4);
  unsigned short* Wbig  = (unsigned short*)alloc((size_t)512*384*2);
  unsigned short* w2b   = (unsigned short*)alloc(16384*2);
  float*          biasBase = (float*)alloc(512*4);
  float*          uIn   = (float*)alloc(512*4);
  float*          uOut  = (float*)alloc(512*4);
  unsigned char*  cf    = (unsigned char*)alloc(M_);
  int*            nb    = (int*)alloc(512*4);
  int*            nbase = (int*)alloc(513*4);
  int*            vbase = (int*)alloc(513*4);
  if (off > ws_size) return;

  k_prepW<<<512,128,0,stream>>>(w_ih,w_hh,W_in,W_out,b_in,b_out,b_ih,b_hh,
                                b_iah,b_ioh,W2,alias,lens,
                                Wbig,biasBase,uIn,uOut,w2b,nb);
  k_scan<<<1,512,0,stream>>>(nb, lens, nbase, vbase);
  k_aggemb<<<B_,1024,0,stream>>>(alias, items, lens, emb, nb, nbase, vbase,
                                 X3, cf, gidx);
  k_gates_q0<<<800,512,0,stream>>>(X3, Wbig, w2b, biasBase, uIn, uOut, cf,
                                   hidden, q0n, nbase+512);
  k_attn<<<B_,1024,0,stream>>>(q0n, hidden, gidx, lens, vbase, W1, g_q, beta_q,
                               W3, g_sh, beta_sh, Wt, (float*)d_out);
}

// Round 13
// 177.358 us; speedup vs baseline: 1.1483x; 1.1483x over previous
//
#include <hip/hip_runtime.h>
#include <hip/hip_bf16.h>
#include <cstdint>
#include <cstddef>

#define B_ 512
#define L_ 200
#define D_ 128
#define M_ (B_*L_)
#define T_ 4

typedef short bf16x8 __attribute__((ext_vector_type(8)));
typedef unsigned short u16x8 __attribute__((ext_vector_type(8)));
typedef float f32x4 __attribute__((ext_vector_type(4)));

__device__ __forceinline__ float bf2f(unsigned short u){
  union { unsigned int i; float f; } c; c.i = ((unsigned int)u)<<16; return c.f;
}
__device__ __forceinline__ unsigned short f2bf(float f){
  union { float f; unsigned int i; } c; c.f = f;
  unsigned int r = c.i + 0x7FFFu + ((c.i>>16)&1u);
  return (unsigned short)(r>>16);
}
__device__ __forceinline__ float wsum(float v){
  #pragma unroll
  for (int m=1;m<64;m<<=1) v += __shfl_xor(v, m, 64);
  return v;
}
__device__ __forceinline__ void gload_lds16(const void* g, void* l){
  __builtin_amdgcn_global_load_lds(
      (const __attribute__((address_space(1))) void*)g,
      (__attribute__((address_space(3))) void*)l, 16, 0, 0);
}

// ---------------------------------------------------------------------------
// bf16 GEMM (Q0 = hidden[gidx] @ W2^T), 128x128 tile, BK=32, 2-phase staging.
// Row indirection via gidx (global src of global_load_lds is per-lane).
// ---------------------------------------------------------------------------
__global__ __launch_bounds__(256)
void gemm_bt(const unsigned short* __restrict__ A, int lda,
             const unsigned short* __restrict__ Bt, int ldb,
             const float* __restrict__ bias,
             unsigned short* __restrict__ C, int ldc, int K,
             const int* __restrict__ mlimit, const int* __restrict__ gidx)
{
  const int m0 = blockIdx.y * 128;
  const int Mv = mlimit ? *mlimit : (1<<30);
  if (m0 >= Mv) return;
  __shared__ __align__(16) short sAs[2][128*32];
  __shared__ __align__(16) short sBs[2][128*32];
  const int tid = threadIdx.x;
  const int n0 = blockIdx.x * 128;
  const int lane = tid & 63;
  const int w = tid >> 6;
  const int wr = (w>>1)*64, wc = (w&1)*64;

  f32x4 acc[4][4];
  #pragma unroll
  for (int i=0;i<4;i++)
    #pragma unroll
    for (int j=0;j<4;j++) acc[i][j] = (f32x4){0.f,0.f,0.f,0.f};

  const int c1 = tid, c2 = tid + 256;
  const int r1 = c1>>2, s1 = c1&3, k1 = ((s1 ^ ((r1>>1)&3))&3)<<3;
  const int r2 = c2>>2, s2 = c2&3, k2 = ((s2 ^ ((r2>>1)&3))&3)<<3;
  int ar1 = m0 + r1, ar2 = m0 + r2;
  if (gidx){ ar1 = (ar1 < Mv) ? gidx[ar1] : 0; ar2 = (ar2 < Mv) ? gidx[ar2] : 0; }
  const int fr = lane & 15;
  const int fq = lane >> 4;
  const int fk = ((fq ^ ((fr>>1)&3))&3)<<3;

  auto stage = [&](int t){
    const int buf = t & 1, ks = t << 5;
    gload_lds16(A  + (size_t)ar1*lda + ks + k1, sAs[buf] + (size_t)c1*8);
    gload_lds16(A  + (size_t)ar2*lda + ks + k2, sAs[buf] + (size_t)c2*8);
    gload_lds16(Bt + (size_t)(n0 + r1)*ldb + ks + k1, sBs[buf] + (size_t)c1*8);
    gload_lds16(Bt + (size_t)(n0 + r2)*ldb + ks + k2, sBs[buf] + (size_t)c2*8);
  };
  const int nT = K >> 5;
  stage(0);
  __syncthreads();
  for (int t=0; t<nT; ++t){
    if (t+1 < nT) stage(t+1);
    const short* a_ = sAs[t&1];
    const short* b_ = sBs[t&1];
    bf16x8 af[4], bfr[4];
    #pragma unroll
    for (int i=0;i<4;i++){
      af[i]  = *(const bf16x8*)(a_ + (wr + i*16 + fr)*32 + fk);
      bfr[i] = *(const bf16x8*)(b_ + (wc + i*16 + fr)*32 + fk);
    }
    #pragma unroll
    for (int i=0;i<4;i++)
      #pragma unroll
      for (int j=0;j<4;j++)
        acc[i][j] = __builtin_amdgcn_mfma_f32_16x16x32_bf16(af[i], bfr[j], acc[i][j], 0,0,0);
    __syncthreads();
  }

  const int orow = fq<<2;
  #pragma unroll
  for (int i=0;i<4;i++){
    #pragma unroll
    for (int j=0;j<4;j++){
      const int gn = n0 + wc + j*16 + fr;
      const float bv = bias ? bias[gn] : 0.f;
      #pragma unroll
      for (int v=0;v<4;v++){
        const int gm = m0 + wr + i*16 + orow + v;
        C[(size_t)gm*ldc + gn] = f2bf(acc[i][j][v] + bv);
      }
    }
  }
}

// ---------------------------------------------------------------------------
// Weight prep: Wbig[512][384] gate-interleaved (p = dim*4+g) + W2 -> bf16,
// + nb[b] = max(alias[b,0:len])+1 (wave 0 tail work).
// ---------------------------------------------------------------------------
__global__ __launch_bounds__(128)
void k_prepW(const float* __restrict__ w_ih, const float* __restrict__ w_hh,
             const float* __restrict__ W_in, const float* __restrict__ W_out,
             const float* __restrict__ b_in, const float* __restrict__ b_out,
             const float* __restrict__ b_ih, const float* __restrict__ b_hh,
             const float* __restrict__ b_iah, const float* __restrict__ b_ioh,
             const float* __restrict__ W2,
             const int* __restrict__ alias, const int* __restrict__ lens,
             unsigned short* __restrict__ Wbig, float* __restrict__ biasBase,
             float* __restrict__ uIn, float* __restrict__ uOut,
             unsigned short* __restrict__ w2b, int* __restrict__ nb)
{
  const int p = blockIdx.x, t = threadIdx.x;
  if (p < 128) w2b[p*128 + t] = f2bf(W2[p*128 + t]);
  const int dim = p>>2, g = p&3;
  const int row = (g==0) ? dim : (g==1) ? 128+dim : 256+dim;
  const bool has_ih = (g!=3), has_hh = (g!=2);
  __shared__ float wl[128], wrg[128], red[3][128];
  wl[t]  = has_ih ? w_ih[(size_t)row*256 + t]       : 0.f;
  wrg[t] = has_ih ? w_ih[(size_t)row*256 + 128 + t] : 0.f;
  __syncthreads();
  float cin = 0.f, cout = 0.f;
  if (has_ih) {
    for (int m=0;m<128;m++){
      cin  += wl[m]  * W_in [m*128 + t];
      cout += wrg[m] * W_out[m*128 + t];
    }
  }
  Wbig[(size_t)p*384 +       t] = f2bf(cin);
  Wbig[(size_t)p*384 + 128 + t] = f2bf(cout);
  Wbig[(size_t)p*384 + 256 + t] = f2bf(has_hh ? w_hh[(size_t)row*128 + t] : 0.f);
  red[0][t] = wl[t]*b_iah[t] + wrg[t]*b_ioh[t];
  red[1][t] = wl[t]*b_in[t];
  red[2][t] = wrg[t]*b_out[t];
  __syncthreads();
  if (t == 0) {
    float v=0.f, ui=0.f, uo=0.f;
    for (int k=0;k<128;k++){ v += red[0][k]; ui += red[1][k]; uo += red[2][k]; }
    float bb;
    if (g==0)      bb = b_ih[dim]     + b_hh[dim]     + v;
    else if (g==1) bb = b_ih[128+dim] + b_hh[128+dim] + v;
    else if (g==2) bb = b_ih[256+dim] + v;
    else           bb = b_hh[256+dim];
    biasBase[p] = bb;
    uIn[p]  = has_ih ? ui : 0.f;
    uOut[p] = has_ih ? uo : 0.f;
  }
  if (t < 64) {
    const int len = lens[p];
    int m = 0;
    for (int l=t; l<len; l+=64) m = max(m, alias[p*L_ + l]);
    #pragma unroll
    for (int o=1;o<64;o<<=1) m = max(m, __shfl_xor(m, o, 64));
    if (t==0) nb[p] = m + 1;
  }
}

// ---------------------------------------------------------------------------
// Exclusive prefix sums of nb and len -> nbase[513], vbase[513]
// ---------------------------------------------------------------------------
__global__ __launch_bounds__(512)
void k_scan(const int* __restrict__ nb, const int* __restrict__ lens,
            int* __restrict__ nbase, int* __restrict__ vbase)
{
  __shared__ int A[2][512], Bv[2][512];
  const int t = threadIdx.x;
  const int a0 = nb[t], b0 = lens[t];
  A[0][t] = a0; Bv[0][t] = b0;
  __syncthreads();
  int cur = 0;
  for (int off=1; off<512; off<<=1){
    const int nxt = cur^1;
    A[nxt][t]  = A[cur][t]  + (t>=off ? A[cur][t-off]  : 0);
    Bv[nxt][t] = Bv[cur][t] + (t>=off ? Bv[cur][t-off] : 0);
    __syncthreads();
    cur = nxt;
  }
  nbase[t] = A[cur][t] - a0;
  vbase[t] = Bv[cur][t] - b0;
  if (t==511){ nbase[512] = A[cur][511]; vbase[512] = Bv[cur][511]; }
}

// ---------------------------------------------------------------------------
// Fused embedding gather + graph aggregation -> COMPACT X3 rows + gidx map.
// ---------------------------------------------------------------------------
__global__ __launch_bounds__(1024)
void k_aggemb(const int* __restrict__ alias, const int* __restrict__ items,
              const int* __restrict__ lens, const float* __restrict__ emb,
              const int* __restrict__ nb, const int* __restrict__ nbase,
              const int* __restrict__ vbase,
              unsigned short* __restrict__ X3, unsigned char* __restrict__ cf,
              int* __restrict__ gidx)
{
  const int b = blockIdx.x, tid = threadIdx.x;
  __shared__ unsigned short hl[L_*128];        // 50KB
  __shared__ int al[L_], it[L_];
  __shared__ unsigned bmIn[L_*8], bmOut[L_*8]; // 12.8KB
  if (tid < L_) { al[tid] = alias[b*L_ + tid]; it[tid] = items[b*L_ + tid]; }
  for (int i=tid; i<L_*8; i+=1024){ bmIn[i]=0u; bmOut[i]=0u; }
  __syncthreads();
  const int len = lens[b], nB = nb[b], base = nbase[b];
  if (tid < len) gidx[vbase[b] + tid] = base + al[tid];
  if (tid < len-1) {
    const int r = al[tid], c = al[tid+1];
    atomicOr(&bmIn[c*8 + (r>>5)],  1u<<(r&31));
    atomicOr(&bmOut[r*8 + (c>>5)], 1u<<(c&31));
  }
  const int rr = tid>>5, cc = (tid&31)<<2;
  for (int s=0; s<nB; s+=32) {
    const int j = s + rr;
    if (j < nB) {
      const float4 v = *(const float4*)(emb + (size_t)it[j]*128 + cc);
      ushort4 o; o.x=f2bf(v.x); o.y=f2bf(v.y); o.z=f2bf(v.z); o.w=f2bf(v.w);
      *(ushort4*)(hl + j*128 + cc) = o;
      *(ushort4*)(X3 + (size_t)(base + j)*384 + 256 + cc) = o;
    }
  }
  __syncthreads();
  const int g = tid >> 7, d = tid & 127;
  for (int s=0; s<nB; s+=8) {
    const int i = s + g;
    if (i < nB) {
      float si=0.f, so=0.f; int ci=0, co=0;
      #pragma unroll
      for (int wd=0; wd<8; ++wd) {
        unsigned word = bmIn[i*8+wd];
        while (word) { int j = __ffs(word)-1; word &= word-1u;
          si += bf2f(hl[(wd*32+j)*128 + d]); ci++; }
        word = bmOut[i*8+wd];
        while (word) { int j = __ffs(word)-1; word &= word-1u;
          so += bf2f(hl[(wd*32+j)*128 + d]); co++; }
      }
      unsigned short* xr = X3 + (size_t)(base + i)*384;
      xr[d]       = f2bf(si / (float)(ci>0?ci:1));
      xr[128 + d] = f2bf(so / (float)(co>0?co:1));
      if (d == 0) cf[base + i] = (unsigned char)((ci>0?1:0) | (co>0?2:0));
    }
  }
}

// ---------------------------------------------------------------------------
// Fused gates GEMM + GRU over COMPACT rows, register-only epilogue,
// 2-phase double-buffered staging (R10-proven). 48KB LDS -> 3 blocks/CU.
// ---------------------------------------------------------------------------
__global__ __launch_bounds__(512)
void k_gates_gru(const unsigned short* __restrict__ X3,
                 const unsigned short* __restrict__ Wbig,
                 const float* __restrict__ biasBase,
                 const float* __restrict__ uIn,
                 const float* __restrict__ uOut,
                 const unsigned char* __restrict__ cf,
                 unsigned short* __restrict__ hidden,
                 const int* __restrict__ mlimit)
{
  const int m0 = blockIdx.y * 128;
  if (m0 >= *mlimit) return;
  __shared__ __align__(16) short sA[2][128*32];   // 16KB
  __shared__ __align__(16) short sB[2][256*32];   // 32KB
  const int tid = threadIdx.x;
  const int p0 = blockIdx.x * 256;
  const int lane = tid & 63;
  const int w = tid >> 6;
  const int wr  = (w>>2)*64;
  const int wcp = (w&3)*64;
  const int fr = lane & 15;
  const int fq = lane >> 4;
  const int fk = ((fq ^ ((fr>>1)&3))&3)<<3;

  f32x4 acc[4][4];
  #pragma unroll
  for (int i=0;i<4;i++)
    #pragma unroll
    for (int j=0;j<4;j++) acc[i][j] = (f32x4){0.f,0.f,0.f,0.f};

  const int ra = tid>>2, sa_ = tid&3, ka = ((sa_ ^ ((ra>>1)&3))&3)<<3;
  const int c1 = tid + 512, rb1 = c1>>2, sb1 = c1&3, kb1 = ((sb1 ^ ((rb1>>1)&3))&3)<<3;

  auto stage = [&](int t){
    const int buf = t & 1, ks = t << 5;
    gload_lds16(X3   + (size_t)(m0 + ra )*384 + ks + ka , sA[buf] + (size_t)tid*8);
    gload_lds16(Wbig + (size_t)(p0 + ra )*384 + ks + ka , sB[buf] + (size_t)tid*8);
    gload_lds16(Wbig + (size_t)(p0 + rb1)*384 + ks + kb1, sB[buf] + (size_t)(c1-512)*8 + 512*8);
  };
  stage(0);
  __syncthreads();
  for (int t=0; t<12; ++t){
    if (t < 11) stage(t+1);
    const short* a_ = sA[t&1];
    const short* b_ = sB[t&1];
    bf16x8 af[4], bfr[4];
    #pragma unroll
    for (int i=0;i<4;i++){
      af[i]  = *(const bf16x8*)(a_ + (wr  + i*16 + fr)*32 + fk);
      bfr[i] = *(const bf16x8*)(b_ + (wcp + i*16 + fr)*32 + fk);
    }
    #pragma unroll
    for (int i=0;i<4;i++)
      #pragma unroll
      for (int j=0;j<4;j++)
        acc[i][j] = __builtin_amdgcn_mfma_f32_16x16x32_bf16(af[i], bfr[j], acc[i][j], 0,0,0);
    __syncthreads();
  }

  // Epilogue: 4x4 quad transpose -> all gates in one lane -> GRU -> hidden.
  const bool q0b = (lane & 1), q1b = (lane & 2);
  #pragma unroll
  for (int j=0;j<4;j++){
    const int dim = (p0>>2) + (w&3)*16 + j*4 + ((lane>>2)&3);
    const float4 bb = *(const float4*)(biasBase + dim*4);
    const float4 bi = *(const float4*)(uIn  + dim*4);
    const float4 bo = *(const float4*)(uOut + dim*4);
    #pragma unroll
    for (int i=0;i<4;i++){
      const float a0=acc[i][j][0], a1=acc[i][j][1], a2=acc[i][j][2], a3=acc[i][j][3];
      const float t0=__shfl_xor(a0,1), t1=__shfl_xor(a1,1), t2=__shfl_xor(a2,1), t3=__shfl_xor(a3,1);
      const float s0 = q0b? t1:a0, s1 = q0b? a1:t0, s2 = q0b? t3:a2, s3 = q0b? a3:t2;
      const float u0=__shfl_xor(s0,2), u1=__shfl_xor(s1,2), u2=__shfl_xor(s2,2), u3=__shfl_xor(s3,2);
      float G0 = q1b? u2:s0, G1 = q1b? u3:s1, G2 = q1b? s2:u0, G3 = q1b? s3:u1;
      const int row = m0 + wr + i*16 + fq*4 + (lane&3);
      const unsigned c = cf[row];
      const float fi = (c&1) ? 1.f : 0.f, fo = (c&2) ? 1.f : 0.f;
      G0 += bb.x + fi*bi.x + fo*bo.x;
      G1 += bb.y + fi*bi.y + fo*bo.y;
      G2 += bb.z + fi*bi.z + fo*bo.z;
      G3 += bb.w;
      const float h = bf2f(X3[(size_t)row*384 + 256 + dim]);
      const float r = 1.f/(1.f+__expf(-G0));
      const float z = 1.f/(1.f+__expf(-G1));
      const float x = G2 + r*G3;
      const float n = 1.f - 2.f/(__expf(2.f*x)+1.f);   // tanh
      hidden[(size_t)row*128 + dim] = f2bf((1.f-z)*h + z*n);
    }
  }
}

// ---------------------------------------------------------------------------
// LN + LIF + alpha + masked sum over compact valid rows, THEN the final
// sh=[a,ht] LIF + LN + @Wt.T + mean_T — all in one per-batch block.
// Reductions fused: one butterfly over (Σx, Σx²); one over the 4 alpha
// partials (dependency depth 36 -> 12 levels).
// ---------------------------------------------------------------------------
__global__ __launch_bounds__(1024)
void k_attn(const unsigned short* __restrict__ Q0,
            const unsigned short* __restrict__ hidden, const int* __restrict__ gidx,
            const int* __restrict__ lens, const int* __restrict__ vbase,
            const float* __restrict__ W1,
            const float* __restrict__ g_q, const float* __restrict__ beta_q,
            const float* __restrict__ W3,
            const float* __restrict__ g_sh, const float* __restrict__ beta_sh,
            const float* __restrict__ Wt, float* __restrict__ out)
{
  const int b = blockIdx.x, tid = threadIdx.x;
  const int w = tid>>6, lane = tid&63;
  __shared__ float a_acc[16][T_][128];
  __shared__ float htv[128], htw[128];
  __shared__ float ys[256];
  __shared__ float part[T_][4];
  const int len = lens[b], vb = vbase[b];
  for (int i=tid; i<16*T_*128; i+=1024) ((float*)a_acc)[i] = 0.f;
  if (tid < 128) htv[tid] = bf2f(hidden[(size_t)gidx[vb + len - 1]*128 + tid]);
  __syncthreads();
  {  // htw[d] = sum_k W1[d][k] * htv[k]; 8 threads per dim.
    const int d = tid >> 3, seg = (tid & 7) << 4;
    const float* wr1 = W1 + (size_t)d*128 + seg;
    const float* hv = htv + seg;
    float p = 0.f;
    #pragma unroll
    for (int k=0;k<16;k++) p += wr1[k]*hv[k];
    p += __shfl_xor(p, 1, 64); p += __shfl_xor(p, 2, 64); p += __shfl_xor(p, 4, 64);
    if ((tid & 7) == 0) htw[d] = p;
  }
  __syncthreads();
  const float h0 = htw[lane], h1 = htw[lane+64];
  const float gq0 = g_q[lane], gq1 = g_q[lane+64];
  const float bq0 = beta_q[lane], bq1 = beta_q[lane+64];
  const float w30 = W3[lane], w31 = W3[lane+64];
  for (int l = w; l < len; l += 16) {
    const size_t row = (size_t)(vb + l);
    const size_t hrow = (size_t)gidx[row];
    const float q0 = bf2f(Q0[row*128 + lane]) + h0;
    const float q1 = bf2f(Q0[row*128 + lane + 64]) + h1;
    // fused mean/var butterfly: (Σx, Σx²)
    float s1 = q0 + q1, s2 = q0*q0 + q1*q1;
    #pragma unroll
    for (int mm=1;mm<64;mm<<=1){
      s1 += __shfl_xor(s1, mm, 64);
      s2 += __shfl_xor(s2, mm, 64);
    }
    const float m = s1 * (1.f/128.f);
    const float var = fmaxf(s2 * (1.f/128.f) - m*m, 0.f);
    const float inv = rsqrtf(var + 1e-5f);
    const float x0 = (q0-m)*inv*gq0 + bq0;
    const float x1 = (q1-m)*inv*gq1 + bq1;
    const float sh0 = bf2f(hidden[hrow*128+lane]), sh1 = bf2f(hidden[hrow*128+lane+64]);
    // LIF -> per-lane alpha partials, then one 4-wide butterfly
    float pa[T_];
    float v0=0.f, v1=0.f;
    #pragma unroll
    for (int t=0;t<T_;t++){
      v0 = 0.5f*(v0+x0); v1 = 0.5f*(v1+x1);
      const float s0 = (v0>=1.f)?1.f:0.f, s1v = (v1>=1.f)?1.f:0.f;
      v0 -= s0*v0; v1 -= s1v*v1;
      pa[t] = s0*w30 + s1v*w31;
    }
    #pragma unroll
    for (int mm=1;mm<64;mm<<=1){
      pa[0] += __shfl_xor(pa[0], mm, 64);
      pa[1] += __shfl_xor(pa[1], mm, 64);
      pa[2] += __shfl_xor(pa[2], mm, 64);
      pa[3] += __shfl_xor(pa[3], mm, 64);
    }
    #pragma unroll
    for (int t=0;t<T_;t++){
      a_acc[w][t][lane]    += pa[t]*sh0;
      a_acc[w][t][lane+64] += pa[t]*sh1;
    }
  }
  __syncthreads();

  // ---- final stage: sh=[a,ht] LIF, LN(binary), @Wt, mean_T ----
  float sp[T_] = {0.f,0.f,0.f,0.f};
  if (tid < 256) {
    const float xh = (tid >= 128) ? htv[tid-128] : 0.f;
    float v = 0.f;
    #pragma unroll
    for (int t=0;t<T_;t++){
      float x;
      if (tid < 128) {
        x = 0.f;
        #pragma unroll
        for (int p=0;p<16;p++) x += a_acc[p][t][tid];
      } else x = xh;
      v = 0.5f*(v + x);
      const float s = (v>=1.f)?1.f:0.f;
      v -= s*v;
      sp[t] = s;
    }
    #pragma unroll
    for (int t=0;t<T_;t++){
      const float r = wsum(sp[t]);
      if (lane==0) part[t][w] = r;
    }
  }
  __syncthreads();
  if (tid < 256) {
    float acc4 = 0.f;
    #pragma unroll
    for (int t=0;t<T_;t++){
      const float k = part[t][0]+part[t][1]+part[t][2]+part[t][3];
      const float mean = k * (1.f/256.f);
      const float varr = mean - mean*mean;   // spikes binary: E[x^2]=E[x]
      const float inv = rsqrtf(varr + 1e-5f);
      acc4 += (sp[t]-mean)*inv;
    }
    ys[tid] = acc4*g_sh[tid] + 4.f*beta_sh[tid];
  }
  __syncthreads();
  if (tid < 128) {
    float acc = 0.f;
    const float4* wr4 = (const float4*)(Wt + (size_t)tid*256);
    const float4* ys4 = (const float4*)ys;
    #pragma unroll 8
    for (int k=0;k<64;k++){
      const float4 wv = wr4[k], yv = ys4[k];
      acc += wv.x*yv.x + wv.y*yv.y + wv.z*yv.z + wv.w*yv.w;
    }
    out[(size_t)b*128 + tid] = acc*0.25f;
  }
}

// ---------------------------------------------------------------------------
extern "C" void kernel_launch(void* const* d_in, const int* in_sizes, int n_in,
                              void* d_out, int out_size, void* d_ws, size_t ws_size,
                              hipStream_t stream)
{
  const int*   alias  = (const int*)d_in[1];
  const int*   items  = (const int*)d_in[2];
  const int*   lens   = (const int*)d_in[4];
  const float* emb    = (const float*)d_in[5];
  const float* W_in   = (const float*)d_in[6];
  const float* b_in   = (const float*)d_in[7];
  const float* W_out  = (const float*)d_in[8];
  const float* b_out  = (const float*)d_in[9];
  const float* w_ih   = (const float*)d_in[10];
  const float* w_hh   = (const float*)d_in[11];
  const float* b_ih   = (const float*)d_in[12];
  const float* b_hh   = (const float*)d_in[13];
  const float* b_iah  = (const float*)d_in[14];
  const float* b_ioh  = (const float*)d_in[15];
  const float* W1     = (const float*)d_in[16];
  const float* W2     = (const float*)d_in[17];
  const float* W3     = (const float*)d_in[18];
  const float* Wt     = (const float*)d_in[19];
  const float* g_q    = (const float*)d_in[20];
  const float* beta_q = (const float*)d_in[21];
  const float* g_sh   = (const float*)d_in[22];
  const float* beta_sh= (const float*)d_in[23];

  char* ws = (char*)d_ws;
  size_t off = 0;
  auto alloc = [&](size_t bytes)->void* {
    void* p = ws + off; off += (bytes + 255) & ~(size_t)255; return p;
  };
  unsigned short* X3    = (unsigned short*)alloc((size_t)M_*384*2);   // compact
  unsigned short* hidden= (unsigned short*)alloc((size_t)M_*128*2);   // compact
  unsigned short* Q0c   = (unsigned short*)alloc((size_t)M_*128*2);   // compact
  int*            gidx  = (int*)alloc((size_t)M_*4);
  unsigned short* Wbig  = (unsigned short*)alloc((size_t)512*384*2);
  unsigned short* w2b   = (unsigned short*)alloc(16384*2);
  float*          biasBase = (float*)alloc(512*4);
  float*          uIn   = (float*)alloc(512*4);
  float*          uOut  = (float*)alloc(512*4);
  unsigned char*  cf    = (unsigned char*)alloc(M_);
  int*            nb    = (int*)alloc(512*4);
  int*            nbase = (int*)alloc(513*4);
  int*            vbase = (int*)alloc(513*4);
  if (off > ws_size) return;

  k_prepW<<<512,128,0,stream>>>(w_ih,w_hh,W_in,W_out,b_in,b_out,b_ih,b_hh,
                                b_iah,b_ioh,W2,alias,lens,
                                Wbig,biasBase,uIn,uOut,w2b,nb);
  k_scan<<<1,512,0,stream>>>(nb, lens, nbase, vbase);
  k_aggemb<<<B_,1024,0,stream>>>(alias, items, lens, emb, nb, nbase, vbase,
                                 X3, cf, gidx);
  k_gates_gru<<<dim3(2,800),512,0,stream>>>(X3, Wbig, biasBase, uIn, uOut, cf,
                                            hidden, nbase+512);
  gemm_bt<<<dim3(1,800),256,0,stream>>>(hidden, 128, w2b, 128, nullptr, Q0c, 128,
                                        128, vbase+512, gidx);
  k_attn<<<B_,1024,0,stream>>>(Q0c, hidden, gidx, lens, vbase, W1, g_q, beta_q,
                               W3, g_sh, beta_sh, Wt, (float*)d_out);
}

// Round 14
// 175.108 us; speedup vs baseline: 1.1630x; 1.0129x over previous
//
#include <hip/hip_runtime.h>
#include <hip/hip_bf16.h>
#include <cstdint>
#include <cstddef>

#define B_ 512
#define L_ 200
#define D_ 128
#define M_ (B_*L_)
#define T_ 4

typedef short bf16x8 __attribute__((ext_vector_type(8)));
typedef unsigned short u16x8 __attribute__((ext_vector_type(8)));
typedef float f32x4 __attribute__((ext_vector_type(4)));

__device__ __forceinline__ float bf2f(unsigned short u){
  union { unsigned int i; float f; } c; c.i = ((unsigned int)u)<<16; return c.f;
}
__device__ __forceinline__ unsigned short f2bf(float f){
  union { float f; unsigned int i; } c; c.f = f;
  unsigned int r = c.i + 0x7FFFu + ((c.i>>16)&1u);
  return (unsigned short)(r>>16);
}
__device__ __forceinline__ float wsum(float v){
  #pragma unroll
  for (int m=1;m<64;m<<=1) v += __shfl_xor(v, m, 64);
  return v;
}
__device__ __forceinline__ void gload_lds16(const void* g, void* l){
  __builtin_amdgcn_global_load_lds(
      (const __attribute__((address_space(1))) void*)g,
      (__attribute__((address_space(3))) void*)l, 16, 0, 0);
}

// ---------------------------------------------------------------------------
// bf16 GEMM (Q0 = hidden[gidx] @ W2^T), 128x128 tile, BK=32, 2-phase staging.
// ---------------------------------------------------------------------------
__global__ __launch_bounds__(256)
void gemm_bt(const unsigned short* __restrict__ A, int lda,
             const unsigned short* __restrict__ Bt, int ldb,
             const float* __restrict__ bias,
             unsigned short* __restrict__ C, int ldc, int K,
             const int* __restrict__ mlimit, const int* __restrict__ gidx)
{
  const int m0 = blockIdx.y * 128;
  const int Mv = mlimit ? *mlimit : (1<<30);
  if (m0 >= Mv) return;
  __shared__ __align__(16) short sAs[2][128*32];
  __shared__ __align__(16) short sBs[2][128*32];
  const int tid = threadIdx.x;
  const int n0 = blockIdx.x * 128;
  const int lane = tid & 63;
  const int w = tid >> 6;
  const int wr = (w>>1)*64, wc = (w&1)*64;

  f32x4 acc[4][4];
  #pragma unroll
  for (int i=0;i<4;i++)
    #pragma unroll
    for (int j=0;j<4;j++) acc[i][j] = (f32x4){0.f,0.f,0.f,0.f};

  const int c1 = tid, c2 = tid + 256;
  const int r1 = c1>>2, s1 = c1&3, k1 = ((s1 ^ ((r1>>1)&3))&3)<<3;
  const int r2 = c2>>2, s2 = c2&3, k2 = ((s2 ^ ((r2>>1)&3))&3)<<3;
  int ar1 = m0 + r1, ar2 = m0 + r2;
  if (gidx){ ar1 = (ar1 < Mv) ? gidx[ar1] : 0; ar2 = (ar2 < Mv) ? gidx[ar2] : 0; }
  const int fr = lane & 15;
  const int fq = lane >> 4;
  const int fk = ((fq ^ ((fr>>1)&3))&3)<<3;

  auto stage = [&](int t){
    const int buf = t & 1, ks = t << 5;
    gload_lds16(A  + (size_t)ar1*lda + ks + k1, sAs[buf] + (size_t)c1*8);
    gload_lds16(A  + (size_t)ar2*lda + ks + k2, sAs[buf] + (size_t)c2*8);
    gload_lds16(Bt + (size_t)(n0 + r1)*ldb + ks + k1, sBs[buf] + (size_t)c1*8);
    gload_lds16(Bt + (size_t)(n0 + r2)*ldb + ks + k2, sBs[buf] + (size_t)c2*8);
  };
  const int nT = K >> 5;
  stage(0);
  __syncthreads();
  for (int t=0; t<nT; ++t){
    if (t+1 < nT) stage(t+1);
    const short* a_ = sAs[t&1];
    const short* b_ = sBs[t&1];
    bf16x8 af[4], bfr[4];
    #pragma unroll
    for (int i=0;i<4;i++){
      af[i]  = *(const bf16x8*)(a_ + (wr + i*16 + fr)*32 + fk);
      bfr[i] = *(const bf16x8*)(b_ + (wc + i*16 + fr)*32 + fk);
    }
    #pragma unroll
    for (int i=0;i<4;i++)
      #pragma unroll
      for (int j=0;j<4;j++)
        acc[i][j] = __builtin_amdgcn_mfma_f32_16x16x32_bf16(af[i], bfr[j], acc[i][j], 0,0,0);
    __syncthreads();
  }

  const int orow = fq<<2;
  #pragma unroll
  for (int i=0;i<4;i++){
    #pragma unroll
    for (int j=0;j<4;j++){
      const int gn = n0 + wc + j*16 + fr;
      const float bv = bias ? bias[gn] : 0.f;
      #pragma unroll
      for (int v=0;v<4;v++){
        const int gm = m0 + wr + i*16 + orow + v;
        C[(size_t)gm*ldc + gn] = f2bf(acc[i][j][v] + bv);
      }
    }
  }
}

// ---------------------------------------------------------------------------
// Weight prep: Wbig[512][384] gate-interleaved (p = dim*4+g) + W2 -> bf16,
// + nb[b] = max(alias[b,0:len])+1 (wave 0 tail work).
// ---------------------------------------------------------------------------
__global__ __launch_bounds__(128)
void k_prepW(const float* __restrict__ w_ih, const float* __restrict__ w_hh,
             const float* __restrict__ W_in, const float* __restrict__ W_out,
             const float* __restrict__ b_in, const float* __restrict__ b_out,
             const float* __restrict__ b_ih, const float* __restrict__ b_hh,
             const float* __restrict__ b_iah, const float* __restrict__ b_ioh,
             const float* __restrict__ W2,
             const int* __restrict__ alias, const int* __restrict__ lens,
             unsigned short* __restrict__ Wbig, float* __restrict__ biasBase,
             float* __restrict__ uIn, float* __restrict__ uOut,
             unsigned short* __restrict__ w2b, int* __restrict__ nb)
{
  const int p = blockIdx.x, t = threadIdx.x;
  if (p < 128) w2b[p*128 + t] = f2bf(W2[p*128 + t]);
  const int dim = p>>2, g = p&3;
  const int row = (g==0) ? dim : (g==1) ? 128+dim : 256+dim;
  const bool has_ih = (g!=3), has_hh = (g!=2);
  __shared__ float wl[128], wrg[128], red[3][128];
  wl[t]  = has_ih ? w_ih[(size_t)row*256 + t]       : 0.f;
  wrg[t] = has_ih ? w_ih[(size_t)row*256 + 128 + t] : 0.f;
  __syncthreads();
  float cin = 0.f, cout = 0.f;
  if (has_ih) {
    for (int m=0;m<128;m++){
      cin  += wl[m]  * W_in [m*128 + t];
      cout += wrg[m] * W_out[m*128 + t];
    }
  }
  Wbig[(size_t)p*384 +       t] = f2bf(cin);
  Wbig[(size_t)p*384 + 128 + t] = f2bf(cout);
  Wbig[(size_t)p*384 + 256 + t] = f2bf(has_hh ? w_hh[(size_t)row*128 + t] : 0.f);
  red[0][t] = wl[t]*b_iah[t] + wrg[t]*b_ioh[t];
  red[1][t] = wl[t]*b_in[t];
  red[2][t] = wrg[t]*b_out[t];
  __syncthreads();
  if (t == 0) {
    float v=0.f, ui=0.f, uo=0.f;
    for (int k=0;k<128;k++){ v += red[0][k]; ui += red[1][k]; uo += red[2][k]; }
    float bb;
    if (g==0)      bb = b_ih[dim]     + b_hh[dim]     + v;
    else if (g==1) bb = b_ih[128+dim] + b_hh[128+dim] + v;
    else if (g==2) bb = b_ih[256+dim] + v;
    else           bb = b_hh[256+dim];
    biasBase[p] = bb;
    uIn[p]  = has_ih ? ui : 0.f;
    uOut[p] = has_ih ? uo : 0.f;
  }
  if (t < 64) {
    const int len = lens[p];
    int m = 0;
    for (int l=t; l<len; l+=64) m = max(m, alias[p*L_ + l]);
    #pragma unroll
    for (int o=1;o<64;o<<=1) m = max(m, __shfl_xor(m, o, 64));
    if (t==0) nb[p] = m + 1;
  }
}

// ---------------------------------------------------------------------------
// Fused: in-block prefix scan (nb, lens) + embedding gather + graph
// aggregation -> COMPACT X3 rows + gidx map + nbase/vbase arrays.
// Every block redundantly scans (deterministic; identical global writes).
// ---------------------------------------------------------------------------
__global__ __launch_bounds__(1024)
void k_aggemb(const int* __restrict__ alias, const int* __restrict__ items,
              const int* __restrict__ lens, const float* __restrict__ emb,
              const int* __restrict__ nb,
              unsigned short* __restrict__ X3, unsigned char* __restrict__ cf,
              int* __restrict__ gidx, int* __restrict__ nbase,
              int* __restrict__ vbase)
{
  const int b = blockIdx.x, tid = threadIdx.x;
  __shared__ unsigned short hl[L_*128];        // 50KB
  __shared__ int al[L_], it[L_];
  __shared__ unsigned bmIn[L_*8], bmOut[L_*8]; // 12.8KB
  __shared__ int scN[2][512], scV[2][512];     // 8KB
  if (tid < L_) { al[tid] = alias[b*L_ + tid]; it[tid] = items[b*L_ + tid]; }
  for (int i=tid; i<L_*8; i+=1024){ bmIn[i]=0u; bmOut[i]=0u; }
  if (tid < 512){ scN[0][tid] = nb[tid]; scV[0][tid] = lens[tid]; }
  __syncthreads();
  // inclusive scan over 512 entries
  int cur = 0;
  for (int off=1; off<512; off<<=1){
    const int nxt = cur^1;
    if (tid < 512){
      scN[nxt][tid] = scN[cur][tid] + (tid>=off ? scN[cur][tid-off] : 0);
      scV[nxt][tid] = scV[cur][tid] + (tid>=off ? scV[cur][tid-off] : 0);
    }
    __syncthreads();
    cur = nxt;
  }
  const int len = lens[b], nB = nb[b];
  const int base = scN[cur][b] - nB;          // exclusive
  const int vb   = scV[cur][b] - len;
  if (tid == 0){ nbase[b] = base; vbase[b] = vb; }
  if (tid == 1){ nbase[512] = scN[cur][511]; vbase[512] = scV[cur][511]; }
  if (tid < len) gidx[vb + tid] = base + al[tid];
  if (tid < len-1) {
    const int r = al[tid], c = al[tid+1];
    atomicOr(&bmIn[c*8 + (r>>5)],  1u<<(r&31));
    atomicOr(&bmOut[r*8 + (c>>5)], 1u<<(c&31));
  }
  const int rr = tid>>5, cc = (tid&31)<<2;
  for (int s=0; s<nB; s+=32) {
    const int j = s + rr;
    if (j < nB) {
      const float4 v = *(const float4*)(emb + (size_t)it[j]*128 + cc);
      ushort4 o; o.x=f2bf(v.x); o.y=f2bf(v.y); o.z=f2bf(v.z); o.w=f2bf(v.w);
      *(ushort4*)(hl + j*128 + cc) = o;
      *(ushort4*)(X3 + (size_t)(base + j)*384 + 256 + cc) = o;
    }
  }
  __syncthreads();
  const int g = tid >> 7, d = tid & 127;
  for (int s=0; s<nB; s+=8) {
    const int i = s + g;
    if (i < nB) {
      float si=0.f, so=0.f; int ci=0, co=0;
      #pragma unroll
      for (int wd=0; wd<8; ++wd) {
        unsigned word = bmIn[i*8+wd];
        while (word) { int j = __ffs(word)-1; word &= word-1u;
          si += bf2f(hl[(wd*32+j)*128 + d]); ci++; }
        word = bmOut[i*8+wd];
        while (word) { int j = __ffs(word)-1; word &= word-1u;
          so += bf2f(hl[(wd*32+j)*128 + d]); co++; }
      }
      unsigned short* xr = X3 + (size_t)(base + i)*384;
      xr[d]       = f2bf(si / (float)(ci>0?ci:1));
      xr[128 + d] = f2bf(so / (float)(co>0?co:1));
      if (d == 0) cf[base + i] = (unsigned char)((ci>0?1:0) | (co>0?2:0));
    }
  }
}

// ---------------------------------------------------------------------------
// Fused gates GEMM + GRU over COMPACT rows, register-only epilogue,
// 2-phase double-buffered staging (R10-proven). 48KB LDS -> 3 blocks/CU.
// Epilogue h-reads staged into dead sB via coalesced chunk-swizzled
// global_load_lds (linear dest + inverse-swizzled src + swizzled read).
// ---------------------------------------------------------------------------
__global__ __launch_bounds__(512)
void k_gates_gru(const unsigned short* __restrict__ X3,
                 const unsigned short* __restrict__ Wbig,
                 const float* __restrict__ biasBase,
                 const float* __restrict__ uIn,
                 const float* __restrict__ uOut,
                 const unsigned char* __restrict__ cf,
                 unsigned short* __restrict__ hidden,
                 const int* __restrict__ mlimit)
{
  const int m0 = blockIdx.y * 128;
  if (m0 >= *mlimit) return;
  __shared__ __align__(16) short sA[2][128*32];   // 16KB
  __shared__ __align__(16) short sB[2][256*32];   // 32KB
  const int tid = threadIdx.x;
  const int p0 = blockIdx.x * 256;
  const int lane = tid & 63;
  const int w = tid >> 6;
  const int wr  = (w>>2)*64;
  const int wcp = (w&3)*64;
  const int fr = lane & 15;
  const int fq = lane >> 4;
  const int fk = ((fq ^ ((fr>>1)&3))&3)<<3;

  f32x4 acc[4][4];
  #pragma unroll
  for (int i=0;i<4;i++)
    #pragma unroll
    for (int j=0;j<4;j++) acc[i][j] = (f32x4){0.f,0.f,0.f,0.f};

  const int ra = tid>>2, sa_ = tid&3, ka = ((sa_ ^ ((ra>>1)&3))&3)<<3;
  const int c1 = tid + 512, rb1 = c1>>2, sb1 = c1&3, kb1 = ((sb1 ^ ((rb1>>1)&3))&3)<<3;

  auto stage = [&](int t){
    const int buf = t & 1, ks = t << 5;
    gload_lds16(X3   + (size_t)(m0 + ra )*384 + ks + ka , sA[buf] + (size_t)tid*8);
    gload_lds16(Wbig + (size_t)(p0 + ra )*384 + ks + ka , sB[buf] + (size_t)tid*8);
    gload_lds16(Wbig + (size_t)(p0 + rb1)*384 + ks + kb1, sB[buf] + (size_t)(c1-512)*8 + 512*8);
  };
  stage(0);
  __syncthreads();
  for (int t=0; t<12; ++t){
    if (t < 11) stage(t+1);
    const short* a_ = sA[t&1];
    const short* b_ = sB[t&1];
    bf16x8 af[4], bfr[4];
    #pragma unroll
    for (int i=0;i<4;i++){
      af[i]  = *(const bf16x8*)(a_ + (wr  + i*16 + fr)*32 + fk);
      bfr[i] = *(const bf16x8*)(b_ + (wcp + i*16 + fr)*32 + fk);
    }
    #pragma unroll
    for (int i=0;i<4;i++)
      #pragma unroll
      for (int j=0;j<4;j++)
        acc[i][j] = __builtin_amdgcn_mfma_f32_16x16x32_bf16(af[i], bfr[j], acc[i][j], 0,0,0);
    __syncthreads();
  }

  // Stage the 128-row x 64-dim h-subtile this block needs into dead sB.
  // Logical layout: sH[rl][dl] with 16B chunks swizzled by chunk' = cc ^ (rl&7).
  short* sH = &sB[0][0];   // 16KB
  const int dbase = p0 >> 2;            // 0 or 64
  #pragma unroll
  for (int q=0;q<2;q++){
    const int c = tid + q*512;          // 0..1023 = 128 rows x 8 chunks
    const int rowl = c >> 3, ccp = c & 7;
    const int ccs = ccp ^ (rowl & 7);
    gload_lds16(X3 + (size_t)(m0 + rowl)*384 + 256 + dbase + ccs*8,
                sH + (size_t)c*8);
  }
  __syncthreads();

  // Epilogue: 4x4 quad transpose -> all gates in one lane -> GRU -> hidden.
  const bool q0b = (lane & 1), q1b = (lane & 2);
  #pragma unroll
  for (int j=0;j<4;j++){
    const int dim = dbase + (w&3)*16 + j*4 + ((lane>>2)&3);
    const int dl = dim - dbase;
    const float4 bb = *(const float4*)(biasBase + dim*4);
    const float4 bi = *(const float4*)(uIn  + dim*4);
    const float4 bo = *(const float4*)(uOut + dim*4);
    #pragma unroll
    for (int i=0;i<4;i++){
      const float a0=acc[i][j][0], a1=acc[i][j][1], a2=acc[i][j][2], a3=acc[i][j][3];
      const float t0=__shfl_xor(a0,1), t1=__shfl_xor(a1,1), t2=__shfl_xor(a2,1), t3=__shfl_xor(a3,1);
      const float s0 = q0b? t1:a0, s1 = q0b? a1:t0, s2 = q0b? t3:a2, s3 = q0b? a3:t2;
      const float u0=__shfl_xor(s0,2), u1=__shfl_xor(s1,2), u2=__shfl_xor(s2,2), u3=__shfl_xor(s3,2);
      float G0 = q1b? u2:s0, G1 = q1b? u3:s1, G2 = q1b? s2:u0, G3 = q1b? s3:u1;
      const int row = m0 + wr + i*16 + fq*4 + (lane&3);
      const int rl = row - m0;
      const unsigned c = cf[row];
      const float fi = (c&1) ? 1.f : 0.f, fo = (c&2) ? 1.f : 0.f;
      G0 += bb.x + fi*bi.x + fo*bo.x;
      G1 += bb.y + fi*bi.y + fo*bo.y;
      G2 += bb.z + fi*bi.z + fo*bo.z;
      G3 += bb.w;
      const float h = bf2f((unsigned short)
          sH[rl*64 + (((dl>>3) ^ (rl&7))<<3) + (dl&7)]);
      const float r = 1.f/(1.f+__expf(-G0));
      const float z = 1.f/(1.f+__expf(-G1));
      const float x = G2 + r*G3;
      const float n = 1.f - 2.f/(__expf(2.f*x)+1.f);   // tanh
      hidden[(size_t)row*128 + dim] = f2bf((1.f-z)*h + z*n);
    }
  }
}

// ---------------------------------------------------------------------------
// LN + LIF + alpha + masked sum over compact valid rows, THEN the final
// sh=[a,ht] LIF + LN + @Wt.T + mean_T — all in one per-batch block.
// ---------------------------------------------------------------------------
__global__ __launch_bounds__(1024)
void k_attn(const unsigned short* __restrict__ Q0,
            const unsigned short* __restrict__ hidden, const int* __restrict__ gidx,
            const int* __restrict__ lens, const int* __restrict__ vbase,
            const float* __restrict__ W1,
            const float* __restrict__ g_q, const float* __restrict__ beta_q,
            const float* __restrict__ W3,
            const float* __restrict__ g_sh, const float* __restrict__ beta_sh,
            const float* __restrict__ Wt, float* __restrict__ out)
{
  const int b = blockIdx.x, tid = threadIdx.x;
  const int w = tid>>6, lane = tid&63;
  __shared__ float a_acc[16][T_][128];
  __shared__ float htv[128], htw[128];
  __shared__ float ys[256];
  __shared__ float part[T_][4];
  const int len = lens[b], vb = vbase[b];
  for (int i=tid; i<16*T_*128; i+=1024) ((float*)a_acc)[i] = 0.f;
  if (tid < 128) htv[tid] = bf2f(hidden[(size_t)gidx[vb + len - 1]*128 + tid]);
  __syncthreads();
  {  // htw[d] = sum_k W1[d][k] * htv[k]; 8 threads per dim.
    const int d = tid >> 3, seg = (tid & 7) << 4;
    const float* wr1 = W1 + (size_t)d*128 + seg;
    const float* hv = htv + seg;
    float p = 0.f;
    #pragma unroll
    for (int k=0;k<16;k++) p += wr1[k]*hv[k];
    p += __shfl_xor(p, 1, 64); p += __shfl_xor(p, 2, 64); p += __shfl_xor(p, 4, 64);
    if ((tid & 7) == 0) htw[d] = p;
  }
  __syncthreads();
  const float h0 = htw[lane], h1 = htw[lane+64];
  const float gq0 = g_q[lane], gq1 = g_q[lane+64];
  const float bq0 = beta_q[lane], bq1 = beta_q[lane+64];
  const float w30 = W3[lane], w31 = W3[lane+64];
  for (int l = w; l < len; l += 16) {
    const size_t row = (size_t)(vb + l);
    const size_t hrow = (size_t)gidx[row];
    const float q0 = bf2f(Q0[row*128 + lane]) + h0;
    const float q1 = bf2f(Q0[row*128 + lane + 64]) + h1;
    float s1 = q0 + q1, s2 = q0*q0 + q1*q1;
    #pragma unroll
    for (int mm=1;mm<64;mm<<=1){
      s1 += __shfl_xor(s1, mm, 64);
      s2 += __shfl_xor(s2, mm, 64);
    }
    const float m = s1 * (1.f/128.f);
    const float var = fmaxf(s2 * (1.f/128.f) - m*m, 0.f);
    const float inv = rsqrtf(var + 1e-5f);
    const float x0 = (q0-m)*inv*gq0 + bq0;
    const float x1 = (q1-m)*inv*gq1 + bq1;
    const float sh0 = bf2f(hidden[hrow*128+lane]), sh1 = bf2f(hidden[hrow*128+lane+64]);
    float pa[T_];
    float v0=0.f, v1=0.f;
    #pragma unroll
    for (int t=0;t<T_;t++){
      v0 = 0.5f*(v0+x0); v1 = 0.5f*(v1+x1);
      const float s0 = (v0>=1.f)?1.f:0.f, s1v = (v1>=1.f)?1.f:0.f;
      v0 -= s0*v0; v1 -= s1v*v1;
      pa[t] = s0*w30 + s1v*w31;
    }
    #pragma unroll
    for (int mm=1;mm<64;mm<<=1){
      pa[0] += __shfl_xor(pa[0], mm, 64);
      pa[1] += __shfl_xor(pa[1], mm, 64);
      pa[2] += __shfl_xor(pa[2], mm, 64);
      pa[3] += __shfl_xor(pa[3], mm, 64);
    }
    #pragma unroll
    for (int t=0;t<T_;t++){
      a_acc[w][t][lane]    += pa[t]*sh0;
      a_acc[w][t][lane+64] += pa[t]*sh1;
    }
  }
  __syncthreads();

  // ---- final stage: sh=[a,ht] LIF, LN(binary), @Wt, mean_T ----
  float sp[T_] = {0.f,0.f,0.f,0.f};
  if (tid < 256) {
    const float xh = (tid >= 128) ? htv[tid-128] : 0.f;
    float v = 0.f;
    #pragma unroll
    for (int t=0;t<T_;t++){
      float x;
      if (tid < 128) {
        x = 0.f;
        #pragma unroll
        for (int p=0;p<16;p++) x += a_acc[p][t][tid];
      } else x = xh;
      v = 0.5f*(v + x);
      const float s = (v>=1.f)?1.f:0.f;
      v -= s*v;
      sp[t] = s;
    }
    #pragma unroll
    for (int t=0;t<T_;t++){
      const float r = wsum(sp[t]);
      if (lane==0) part[t][w] = r;
    }
  }
  __syncthreads();
  if (tid < 256) {
    float acc4 = 0.f;
    #pragma unroll
    for (int t=0;t<T_;t++){
      const float k = part[t][0]+part[t][1]+part[t][2]+part[t][3];
      const float mean = k * (1.f/256.f);
      const float varr = mean - mean*mean;   // spikes binary: E[x^2]=E[x]
      const float inv = rsqrtf(varr + 1e-5f);
      acc4 += (sp[t]-mean)*inv;
    }
    ys[tid] = acc4*g_sh[tid] + 4.f*beta_sh[tid];
  }
  __syncthreads();
  if (tid < 128) {
    float acc = 0.f;
    const float4* wr4 = (const float4*)(Wt + (size_t)tid*256);
    const float4* ys4 = (const float4*)ys;
    #pragma unroll 8
    for (int k=0;k<64;k++){
      const float4 wv = wr4[k], yv = ys4[k];
      acc += wv.x*yv.x + wv.y*yv.y + wv.z*yv.z + wv.w*yv.w;
    }
    out[(size_t)b*128 + tid] = acc*0.25f;
  }
}

// ---------------------------------------------------------------------------
extern "C" void kernel_launch(void* const* d_in, const int* in_sizes, int n_in,
                              void* d_out, int out_size, void* d_ws, size_t ws_size,
                              hipStream_t stream)
{
  const int*   alias  = (const int*)d_in[1];
  const int*   items  = (const int*)d_in[2];
  const int*   lens   = (const int*)d_in[4];
  const float* emb    = (const float*)d_in[5];
  const float* W_in   = (const float*)d_in[6];
  const float* b_in   = (const float*)d_in[7];
  const float* W_out  = (const float*)d_in[8];
  const float* b_out  = (const float*)d_in[9];
  const float* w_ih   = (const float*)d_in[10];
  const float* w_hh   = (const float*)d_in[11];
  const float* b_ih   = (const float*)d_in[12];
  const float* b_hh   = (const float*)d_in[13];
  const float* b_iah  = (const float*)d_in[14];
  const float* b_ioh  = (const float*)d_in[15];
  const float* W1     = (const float*)d_in[16];
  const float* W2     = (const float*)d_in[17];
  const float* W3     = (const float*)d_in[18];
  const float* Wt     = (const float*)d_in[19];
  const float* g_q    = (const float*)d_in[20];
  const float* beta_q = (const float*)d_in[21];
  const float* g_sh   = (const float*)d_in[22];
  const float* beta_sh= (const float*)d_in[23];

  char* ws = (char*)d_ws;
  size_t off = 0;
  auto alloc = [&](size_t bytes)->void* {
    void* p = ws + off; off += (bytes + 255) & ~(size_t)255; return p;
  };
  unsigned short* X3    = (unsigned short*)alloc((size_t)M_*384*2);   // compact
  unsigned short* hidden= (unsigned short*)alloc((size_t)M_*128*2);   // compact
  unsigned short* Q0c   = (unsigned short*)alloc((size_t)M_*128*2);   // compact
  int*            gidx  = (int*)alloc((size_t)M_*4);
  unsigned short* Wbig  = (unsigned short*)alloc((size_t)512*384*2);
  unsigned short* w2b   = (unsigned short*)alloc(16384*2);
  float*          biasBase = (float*)alloc(512*4);
  float*          uIn   = (float*)alloc(512*4);
  float*          uOut  = (float*)alloc(512*4);
  unsigned char*  cf    = (unsigned char*)alloc(M_);
  int*            nb    = (int*)alloc(512*4);
  int*            nbase = (int*)alloc(513*4);
  int*            vbase = (int*)alloc(513*4);
  if (off > ws_size) return;

  k_prepW<<<512,128,0,stream>>>(w_ih,w_hh,W_in,W_out,b_in,b_out,b_ih,b_hh,
                                b_iah,b_ioh,W2,alias,lens,
                                Wbig,biasBase,uIn,uOut,w2b,nb);
  k_aggemb<<<B_,1024,0,stream>>>(alias, items, lens, emb, nb,
                                 X3, cf, gidx, nbase, vbase);
  k_gates_gru<<<dim3(2,800),512,0,stream>>>(X3, Wbig, biasBase, uIn, uOut, cf,
                                            hidden, nbase+512);
  gemm_bt<<<dim3(1,800),256,0,stream>>>(hidden, 128, w2b, 128, nullptr, Q0c, 128,
                                        128, vbase+512, gidx);
  k_attn<<<B_,1024,0,stream>>>(Q0c, hidden, gidx, lens, vbase, W1, g_q, beta_q,
                               W3, g_sh, beta_sh, Wt, (float*)d_out);
}